// Round 1
// baseline (1949.769 us; speedup 1.0000x reference)
//
#include <hip/hip_runtime.h>

typedef __attribute__((ext_vector_type(8))) short short8;
typedef __attribute__((ext_vector_type(4))) float f32x4;

#define DEV static __device__ __forceinline__

typedef __attribute__((address_space(1))) void GVoid;
typedef __attribute__((address_space(3))) void LVoid;

DEV unsigned short f2bf(float f) {
  unsigned u = __builtin_bit_cast(unsigned, f);
  u += 0x7fffu + ((u >> 16) & 1u);   // RNE
  return (unsigned short)(u >> 16);
}
DEV float bf2f(unsigned short h) {
  unsigned u = ((unsigned)h) << 16;
  return __builtin_bit_cast(float, u);
}
DEV void cp16(void* lds_uniform_base, const void* gsrc) {
  // async global->LDS, 16B per lane; LDS dest = wave-uniform base + lane*16
  __builtin_amdgcn_global_load_lds((GVoid*)gsrc, (LVoid*)lds_uniform_base, 16, 0, 0);
}

// ---------------------------------------------------------------------------
// Setup: cast weights to bf16 (wqkv concat [768][256], conv perm [co][tap][ci],
// out_w [256][256]) + 256B zero page for conv SAME-padding staging.
// ---------------------------------------------------------------------------
__global__ __launch_bounds__(256) void setup_kernel(
    const float* __restrict__ wq, const float* __restrict__ wk, const float* __restrict__ wv,
    const float* __restrict__ lw, const float* __restrict__ ow,
    unsigned short* __restrict__ wqkvb, unsigned short* __restrict__ w2b,
    unsigned short* __restrict__ woutb, unsigned short* __restrict__ zp)
{
  int i = blockIdx.x * 256 + threadIdx.x;
  if (i < 196608) {
    float f = (i < 65536) ? wq[i] : (i < 131072) ? wk[i - 65536] : wv[i - 131072];
    wqkvb[i] = f2bf(f);
  } else if (i < 786432) {
    int j = i - 196608;
    int co = j / 2304;
    int r = j - co * 2304;
    int tap = r >> 8;
    int ci = r & 255;
    // local_w flat [co][ci][ky][kx] = (co*256+ci)*9 + tap
    w2b[j] = f2bf(lw[(co * 256 + ci) * 9 + tap]);
  } else if (i < 851968) {
    int j = i - 786432;
    woutb[j] = f2bf(ow[j]);
  } else if (i < 852096) {
    zp[i - 851968] = 0;
  }
}

// ---------------------------------------------------------------------------
// ChanLayerNorm -> xn bf16 in window-major layout [n'][256].
// n' = ((b*16+X)*16+Y)*64 + w1*8 + w2 ;  h=X*8+w1, w=Y*8+w2.
// ---------------------------------------------------------------------------
__global__ __launch_bounds__(256) void ln_kernel(
    const float* __restrict__ x, const float* __restrict__ gw,
    const float* __restrict__ bw, unsigned short* __restrict__ xn)
{
  const int t = threadIdx.x;
  const int p = blockIdx.x * 256 + t;
  const int b = p >> 14;
  const int r = p & 16383;
  const int Xw = r >> 10;
  const int r2 = r & 1023;
  const int Yw = r2 >> 6;
  const int tt = r2 & 63;
  const int h = Xw * 8 + (tt >> 3);
  const int w = Yw * 8 + (tt & 7);
  const float* xp = x + ((size_t)b << 22) + h * 128 + w;  // b*256*16384

  float sum = 0.f, ss = 0.f;
#pragma unroll 8
  for (int c = 0; c < 256; ++c) {
    float f = xp[(size_t)c << 14];
    sum += f;
    ss += f * f;
  }
  float mean = sum * (1.f / 256.f);
  float var = ss * (1.f / 256.f) - mean * mean;
  float inv = rsqrtf(var + 1e-5f);

  unsigned short* op = xn + (size_t)p * 256;
#pragma unroll 2
  for (int c = 0; c < 256; c += 4) {
    float f0 = xp[(size_t)(c + 0) << 14];
    float f1 = xp[(size_t)(c + 1) << 14];
    float f2 = xp[(size_t)(c + 2) << 14];
    float f3 = xp[(size_t)(c + 3) << 14];
    float v0 = (f0 - mean) * inv * gw[c + 0] + bw[c + 0];
    float v1 = (f1 - mean) * inv * gw[c + 1] + bw[c + 1];
    float v2 = (f2 - mean) * inv * gw[c + 2] + bw[c + 2];
    float v3 = (f3 - mean) * inv * gw[c + 3] + bw[c + 3];
    unsigned long long pk = (unsigned long long)f2bf(v0) |
                            ((unsigned long long)f2bf(v1) << 16) |
                            ((unsigned long long)f2bf(v2) << 32) |
                            ((unsigned long long)f2bf(v3) << 48);
    *(unsigned long long*)(op + c) = pk;
  }
}

// ---------------------------------------------------------------------------
// Shared MFMA inner: 128x128 block tile, BK=64 (two 32-k steps), 4 waves 2x2.
// LDS tiles stored [16-dim][K] so fragment reads are ds_read_b128.
// ---------------------------------------------------------------------------
DEV void mfma_tile(const unsigned short* As, const unsigned short* Bs,
                   int wm, int wn, int l15, int quad, f32x4 (&acc)[4][4])
{
#pragma unroll
  for (int ks = 0; ks < 2; ++ks) {
    short8 a[4], b[4];
#pragma unroll
    for (int i = 0; i < 4; ++i)
      a[i] = *(const short8*)(As + (wm + i * 16 + l15) * 64 + ks * 32 + quad * 8);
#pragma unroll
    for (int j = 0; j < 4; ++j)
      b[j] = *(const short8*)(Bs + (wn + j * 16 + l15) * 64 + ks * 32 + quad * 8);
#pragma unroll
    for (int i = 0; i < 4; ++i)
#pragma unroll
      for (int j = 0; j < 4; ++j)
        acc[i][j] = __builtin_amdgcn_mfma_f32_16x16x32_bf16(a[i], b[j], acc[i][j], 0, 0, 0);
  }
}

// ---------------------------------------------------------------------------
// QKV projection: [768x256] @ xn[Nc x 256]^T -> q,k,v bf16 [n'][256]
// grid = (6 m-blocks, Nc/128 n-blocks)
// ---------------------------------------------------------------------------
__global__ __launch_bounds__(256) void qkv_gemm(
    const unsigned short* __restrict__ wqkvb, const unsigned short* __restrict__ xn,
    unsigned short* __restrict__ qb, unsigned short* __restrict__ kb,
    unsigned short* __restrict__ vb)
{
  __shared__ __align__(16) unsigned short As[128 * 64];
  __shared__ __align__(16) unsigned short Bs[128 * 64];
  const int tid = threadIdx.x;
  const int lane = tid & 63;
  const int wave = tid >> 6;
  const int l15 = lane & 15;
  const int quad = lane >> 4;
  const int wm = (wave >> 1) * 64;
  const int wn = (wave & 1) * 64;
  const int sub = tid & 7;
  const int row0 = tid >> 3;
  const int m0 = blockIdx.x * 128;
  const int n0 = blockIdx.y * 128;

  f32x4 acc[4][4];
  f32x4 zero = {0.f, 0.f, 0.f, 0.f};
#pragma unroll
  for (int i = 0; i < 4; ++i)
#pragma unroll
    for (int j = 0; j < 4; ++j) acc[i][j] = zero;

  for (int kt = 0; kt < 4; ++kt) {
    const int k0 = kt * 64;
#pragma unroll
    for (int it = 0; it < 4; ++it) {
      const int row = it * 32 + row0;
      cp16(As + (size_t)(it * 256 + wave * 64) * 8,
           wqkvb + (size_t)(m0 + row) * 256 + k0 + sub * 8);
      cp16(Bs + (size_t)(it * 256 + wave * 64) * 8,
           xn + (size_t)(n0 + row) * 256 + k0 + sub * 8);
    }
    __syncthreads();
    mfma_tile(As, Bs, wm, wn, l15, quad, acc);
    __syncthreads();
  }

  unsigned short* ob = (m0 < 256) ? qb : (m0 < 512) ? kb : vb;
  const int chb = (m0 & 255) + wm;
#pragma unroll
  for (int i = 0; i < 4; ++i) {
    const int ch = chb + i * 16 + quad * 4;
#pragma unroll
    for (int j = 0; j < 4; ++j) {
      const int n = n0 + wn + j * 16 + l15;
      unsigned long long pk = (unsigned long long)f2bf(acc[i][j][0]) |
                              ((unsigned long long)f2bf(acc[i][j][1]) << 16) |
                              ((unsigned long long)f2bf(acc[i][j][2]) << 32) |
                              ((unsigned long long)f2bf(acc[i][j][3]) << 48);
      *(unsigned long long*)(ob + (size_t)n * 256 + ch) = pk;
    }
  }
}

// ---------------------------------------------------------------------------
// Windowed attention, fp32 VALU. Block = (window, head-pair), 128 threads.
// Thread = (token, head). k/v staged to LDS as float4; softmax per-thread.
// ---------------------------------------------------------------------------
__global__ __launch_bounds__(128) void attn_kernel(
    const unsigned short* __restrict__ qb, const unsigned short* __restrict__ kb,
    const unsigned short* __restrict__ vb, unsigned short* __restrict__ attnb)
{
  __shared__ float4 ks4[2][64][8];
  __shared__ float4 vs4[2][64][8];
  const int tid = threadIdx.x;
  const int tok = tid & 63;
  const int hs = tid >> 6;  // 0..1
  const int win = blockIdx.x >> 2;
  const int head = (blockIdx.x & 3) * 2 + hs;
  const size_t base = (size_t)(win * 64 + tok) * 256 + head * 32;

  float qf[32];
  {
    const unsigned* qp = (const unsigned*)(qb + base);
    const unsigned* kp = (const unsigned*)(kb + base);
    const unsigned* vp = (const unsigned*)(vb + base);
#pragma unroll
    for (int i = 0; i < 16; ++i) {
      unsigned u = qp[i];
      qf[2 * i] = bf2f((unsigned short)(u & 0xffff));
      qf[2 * i + 1] = bf2f((unsigned short)(u >> 16));
    }
#pragma unroll
    for (int i = 0; i < 8; ++i) {
      unsigned u0 = kp[2 * i], u1 = kp[2 * i + 1];
      float4 f;
      f.x = bf2f((unsigned short)(u0 & 0xffff));
      f.y = bf2f((unsigned short)(u0 >> 16));
      f.z = bf2f((unsigned short)(u1 & 0xffff));
      f.w = bf2f((unsigned short)(u1 >> 16));
      ks4[hs][tok][i] = f;
      unsigned w0 = vp[2 * i], w1 = vp[2 * i + 1];
      float4 g;
      g.x = bf2f((unsigned short)(w0 & 0xffff));
      g.y = bf2f((unsigned short)(w0 >> 16));
      g.z = bf2f((unsigned short)(w1 & 0xffff));
      g.w = bf2f((unsigned short)(w1 >> 16));
      vs4[hs][tok][i] = g;
    }
  }
  __syncthreads();

  float dots[64];
#pragma unroll
  for (int j = 0; j < 64; ++j) {
    float d = 0.f;
#pragma unroll
    for (int c4 = 0; c4 < 8; ++c4) {
      float4 kk = ks4[hs][j][c4];
      d += qf[4 * c4 + 0] * kk.x + qf[4 * c4 + 1] * kk.y +
           qf[4 * c4 + 2] * kk.z + qf[4 * c4 + 3] * kk.w;
    }
    dots[j] = d * 0.17677669529663688f;  // 32^-0.5
  }
  float mx = -1e30f;
#pragma unroll
  for (int j = 0; j < 64; ++j) mx = fmaxf(mx, dots[j]);
  float s = 0.f;
#pragma unroll
  for (int j = 0; j < 64; ++j) {
    float e = __expf(dots[j] - mx);
    dots[j] = e;
    s += e;
  }
  const float rs = 1.f / s;

  float of[32];
#pragma unroll
  for (int c = 0; c < 32; ++c) of[c] = 0.f;
#pragma unroll
  for (int j = 0; j < 64; ++j) {
    const float p = dots[j];
#pragma unroll
    for (int c4 = 0; c4 < 8; ++c4) {
      float4 vv = vs4[hs][j][c4];
      of[4 * c4 + 0] += p * vv.x;
      of[4 * c4 + 1] += p * vv.y;
      of[4 * c4 + 2] += p * vv.z;
      of[4 * c4 + 3] += p * vv.w;
    }
  }
  unsigned* op = (unsigned*)(attnb + base);
#pragma unroll
  for (int i = 0; i < 16; ++i) {
    unsigned u = (unsigned)f2bf(of[2 * i] * rs) |
                 ((unsigned)f2bf(of[2 * i + 1] * rs) << 16);
    op[i] = u;
  }
}

// ---------------------------------------------------------------------------
// 3x3 conv as implicit GEMM (K = 9 taps x 256 ci) + attn add + bias -> sum bf16.
// grid = (2 m-blocks, Nc/128 n-blocks). OOB neighbors load from zero page.
// ---------------------------------------------------------------------------
__global__ __launch_bounds__(256) void conv_gemm(
    const unsigned short* __restrict__ w2b, const unsigned short* __restrict__ vbuf,
    const unsigned short* __restrict__ attnb, const float* __restrict__ lbias,
    const unsigned short* __restrict__ zp, unsigned short* __restrict__ sumb)
{
  __shared__ __align__(16) unsigned short As[128 * 64];
  __shared__ __align__(16) unsigned short Bs[128 * 64];
  const int tid = threadIdx.x;
  const int lane = tid & 63;
  const int wave = tid >> 6;
  const int l15 = lane & 15;
  const int quad = lane >> 4;
  const int wm = (wave >> 1) * 64;
  const int wn = (wave & 1) * 64;
  const int sub = tid & 7;
  const int row0 = tid >> 3;
  const int m0 = blockIdx.x * 128;
  const int n0 = blockIdx.y * 128;

  int bi[4], hh[4], ww[4];
#pragma unroll
  for (int it = 0; it < 4; ++it) {
    int n = n0 + it * 32 + row0;
    int b = n >> 14;
    int r = n & 16383;
    int Xw = r >> 10;
    int r2 = r & 1023;
    int Yw = r2 >> 6;
    int t2 = r2 & 63;
    bi[it] = b;
    hh[it] = Xw * 8 + (t2 >> 3);
    ww[it] = Yw * 8 + (t2 & 7);
  }

  f32x4 acc[4][4];
  f32x4 zero = {0.f, 0.f, 0.f, 0.f};
#pragma unroll
  for (int i = 0; i < 4; ++i)
#pragma unroll
    for (int j = 0; j < 4; ++j) acc[i][j] = zero;

  for (int tap = 0; tap < 9; ++tap) {
    const int dy = tap / 3 - 1;
    const int dx = tap - (tap / 3) * 3 - 1;
    const unsigned short* bp[4];
    int bstep[4];
#pragma unroll
    for (int it = 0; it < 4; ++it) {
      int h2 = hh[it] + dy, w2 = ww[it] + dx;
      bool ok = ((unsigned)h2 < 128u) && ((unsigned)w2 < 128u);
      int nn = ((bi[it] * 16 + (h2 >> 3)) * 16 + (w2 >> 3)) * 64 + (h2 & 7) * 8 + (w2 & 7);
      bp[it] = ok ? (vbuf + (size_t)nn * 256 + sub * 8) : (zp + sub * 8);
      bstep[it] = ok ? 64 : 0;
    }
    for (int cc = 0; cc < 4; ++cc) {
#pragma unroll
      for (int it = 0; it < 4; ++it) {
        cp16(As + (size_t)(it * 256 + wave * 64) * 8,
             w2b + ((size_t)(m0 + it * 32 + row0) * 9 + tap) * 256 + cc * 64 + sub * 8);
        cp16(Bs + (size_t)(it * 256 + wave * 64) * 8, bp[it] + cc * bstep[it]);
      }
      __syncthreads();
      mfma_tile(As, Bs, wm, wn, l15, quad, acc);
      __syncthreads();
    }
  }

#pragma unroll
  for (int i = 0; i < 4; ++i) {
    const int ch = m0 + wm + i * 16 + quad * 4;
    const float b0 = lbias[ch + 0], b1 = lbias[ch + 1], b2 = lbias[ch + 2], b3 = lbias[ch + 3];
#pragma unroll
    for (int j = 0; j < 4; ++j) {
      const int n = n0 + wn + j * 16 + l15;
      const unsigned* ap = (const unsigned*)(attnb + (size_t)n * 256 + ch);
      unsigned a0 = ap[0], a1 = ap[1];
      float r0 = acc[i][j][0] + b0 + bf2f((unsigned short)(a0 & 0xffff));
      float r1 = acc[i][j][1] + b1 + bf2f((unsigned short)(a0 >> 16));
      float r2 = acc[i][j][2] + b2 + bf2f((unsigned short)(a1 & 0xffff));
      float r3 = acc[i][j][3] + b3 + bf2f((unsigned short)(a1 >> 16));
      unsigned long long pk = (unsigned long long)f2bf(r0) |
                              ((unsigned long long)f2bf(r1) << 16) |
                              ((unsigned long long)f2bf(r2) << 32) |
                              ((unsigned long long)f2bf(r3) << 48);
      *(unsigned long long*)(sumb + (size_t)n * 256 + ch) = pk;
    }
  }
}

// ---------------------------------------------------------------------------
// Output projection: out_w[256x256] @ sum[n'][256]^T + out_b -> d_out fp32 NCHW.
// ---------------------------------------------------------------------------
__global__ __launch_bounds__(256) void out_gemm(
    const unsigned short* __restrict__ woutb, const unsigned short* __restrict__ sumb,
    const float* __restrict__ obias, float* __restrict__ out)
{
  __shared__ __align__(16) unsigned short As[128 * 64];
  __shared__ __align__(16) unsigned short Bs[128 * 64];
  const int tid = threadIdx.x;
  const int lane = tid & 63;
  const int wave = tid >> 6;
  const int l15 = lane & 15;
  const int quad = lane >> 4;
  const int wm = (wave >> 1) * 64;
  const int wn = (wave & 1) * 64;
  const int sub = tid & 7;
  const int row0 = tid >> 3;
  const int m0 = blockIdx.x * 128;
  const int n0 = blockIdx.y * 128;

  f32x4 acc[4][4];
  f32x4 zero = {0.f, 0.f, 0.f, 0.f};
#pragma unroll
  for (int i = 0; i < 4; ++i)
#pragma unroll
    for (int j = 0; j < 4; ++j) acc[i][j] = zero;

  for (int kt = 0; kt < 4; ++kt) {
    const int k0 = kt * 64;
#pragma unroll
    for (int it = 0; it < 4; ++it) {
      const int row = it * 32 + row0;
      cp16(As + (size_t)(it * 256 + wave * 64) * 8,
           woutb + (size_t)(m0 + row) * 256 + k0 + sub * 8);
      cp16(Bs + (size_t)(it * 256 + wave * 64) * 8,
           sumb + (size_t)(n0 + row) * 256 + k0 + sub * 8);
    }
    __syncthreads();
    mfma_tile(As, Bs, wm, wn, l15, quad, acc);
    __syncthreads();
  }

  int bb4[4], hw4[4];
#pragma unroll
  for (int j = 0; j < 4; ++j) {
    int n = n0 + wn + j * 16 + l15;
    int b = n >> 14;
    int r = n & 16383;
    int Xw = r >> 10;
    int r2 = r & 1023;
    int Yw = r2 >> 6;
    int t2 = r2 & 63;
    bb4[j] = b;
    hw4[j] = (Xw * 8 + (t2 >> 3)) * 128 + Yw * 8 + (t2 & 7);
  }
#pragma unroll
  for (int i = 0; i < 4; ++i) {
    const int mb = m0 + wm + i * 16 + quad * 4;
    const float o0 = obias[mb + 0], o1 = obias[mb + 1], o2 = obias[mb + 2], o3 = obias[mb + 3];
#pragma unroll
    for (int j = 0; j < 4; ++j) {
      float* o = out + ((size_t)(bb4[j] * 256 + mb) << 14) + hw4[j];
      o[0] = acc[i][j][0] + o0;
      o[(size_t)1 << 14] = acc[i][j][1] + o1;
      o[(size_t)2 << 14] = acc[i][j][2] + o2;
      o[(size_t)3 << 14] = acc[i][j][3] + o3;
    }
  }
}

// ---------------------------------------------------------------------------
extern "C" void kernel_launch(void* const* d_in, const int* in_sizes, int n_in,
                              void* d_out, int out_size, void* d_ws, size_t ws_size,
                              hipStream_t stream)
{
  const float* x  = (const float*)d_in[0];
  const float* g  = (const float*)d_in[1];
  const float* bb = (const float*)d_in[2];
  const float* wq = (const float*)d_in[3];
  const float* wk = (const float*)d_in[4];
  const float* wv = (const float*)d_in[5];
  const float* lw = (const float*)d_in[6];
  const float* lb = (const float*)d_in[7];
  const float* ow = (const float*)d_in[8];
  const float* ob = (const float*)d_in[9];
  float* out = (float*)d_out;

  char* ws = (char*)d_ws;
  unsigned short* wqkvb = (unsigned short*)(ws + 0);        // 393216 B
  unsigned short* w2b   = (unsigned short*)(ws + 393216);   // 1179648 B
  unsigned short* woutb = (unsigned short*)(ws + 1572864);  // 131072 B
  unsigned short* zp    = (unsigned short*)(ws + 1703936);  // 256 B
  const size_t BUF0 = 1704192;

  // images per chunk, sized to ws (4 bf16 buffers of nimg*16384*256 elems)
  int nimg = 16;
  while (nimg > 1 && BUF0 + 4ull * (size_t)nimg * 8388608ull > ws_size) nimg >>= 1;
  const size_t bufB = (size_t)nimg * 8388608ull;
  unsigned short* xnb = (unsigned short*)(ws + BUF0);
  unsigned short* qb  = (unsigned short*)(ws + BUF0 + bufB);
  unsigned short* kb  = (unsigned short*)(ws + BUF0 + 2 * bufB);
  unsigned short* vb  = (unsigned short*)(ws + BUF0 + 3 * bufB);
  unsigned short* attnb = xnb;  // xn dead after qkv
  unsigned short* sumb  = qb;   // q dead after attention

  setup_kernel<<<3329, 256, 0, stream>>>(wq, wk, wv, lw, ow, wqkvb, w2b, woutb, zp);

  const int nchunk = 16 / nimg;
  const int Nc = nimg * 16384;
  for (int c = 0; c < nchunk; ++c) {
    const float* xc = x + (size_t)c * nimg * 256 * 16384;
    float* oc = out + (size_t)c * nimg * 256 * 16384;
    ln_kernel<<<Nc / 256, 256, 0, stream>>>(xc, g, bb, xnb);
    qkv_gemm<<<dim3(6, Nc / 128), 256, 0, stream>>>(wqkvb, xnb, qb, kb, vb);
    attn_kernel<<<(Nc / 64) * 4, 128, 0, stream>>>(qb, kb, vb, attnb);
    conv_gemm<<<dim3(2, Nc / 128), 256, 0, stream>>>(w2b, vb, attnb, lb, zp, sumb);
    out_gemm<<<dim3(2, Nc / 128), 256, 0, stream>>>(woutb, sumb, ob, oc);
  }
}